// Round 16
// baseline (62.394 us; speedup 1.0000x reference)
//
#include <hip/hip_runtime.h>
#include <hip/hip_bf16.h>
#include <math.h>

// Problem constants (from reference):
//   x: (b=8, t=16, c=64, h=56, w=56) f32   -> 25,690,112 elems
//   pos_embedding: (512, 16, 64) f32
//   W_qk: (64, 128) f32  (in, out) ; q = cols 0..63, k = cols 64..127
//   gamma, beta: (64,) f32
// out[b,t,c,f] = sum_j (softmax(q k^T * 0.125)[bc,t,j] + delta_tj) * x[b,j,c,f]
// where bc = b*64 + c, f = h*w = 3136.
//
// R16 = R12 exactly, with ONE change: plain stores instead of
// __builtin_nontemporal_store in the apply phase (A/B test: the NT flag may
// be forcing a slower write path; harness fills hit 7.2 TB/s with plain
// stores). Everything else byte-identical to the proven 61.4 us version.
//
// ws layout: s_ws = 512*16*64 floats (2 MB)

#define HW 3136            // 56*56
#define HW4 784            // HW/4
#define TSTRIDE4 50176     // 64*784, float4 stride between t-planes

// ---------------------------------------------------------------------------
// Kernel 1: pool each (b,t,c) plane 56x56 -> 8x8 (7x7 mean), add pos, write s.
// grid = 8192, block = 256. Swizzle: XCD k owns planes [1024k, 1024k+1024).
// ---------------------------------------------------------------------------
__global__ __launch_bounds__(256) void pool_kernel(const float* __restrict__ x,
                                                   const float* __restrict__ pos,
                                                   float* __restrict__ s_ws) {
    __shared__ float plane[HW];
    const int p   = ((blockIdx.x & 7) << 10) | (blockIdx.x >> 3);  // bijective, 8192%8==0
    const int tid = threadIdx.x;

    const float4* xp = reinterpret_cast<const float4*>(x + (size_t)p * HW);
    float4* pl4 = reinterpret_cast<float4*>(plane);
    #pragma unroll
    for (int k = 0; k < 3; k++) pl4[tid + k * 256] = xp[tid + k * 256];
    if (tid < 16) pl4[768 + tid] = xp[768 + tid];
    __syncthreads();

    if (tid < 64) {
        const int i = tid >> 3, j = tid & 7;          // 8x8 output grid
        const float* base = plane + (i * 7) * 56 + j * 7;
        float sum = 0.f;
        #pragma unroll
        for (int r = 0; r < 7; r++) {
            #pragma unroll
            for (int cc = 0; cc < 7; cc++) sum += base[r * 56 + cc];
        }
        const int c = p & 63, t = (p >> 6) & 15, b = p >> 10;
        const int bc = b * 64 + c;
        const int off = ((bc << 4) + t) * 64 + tid;   // s layout (bc, t, 64)
        s_ws[off] = sum * (1.0f / 49.0f) + pos[off];
    }
}

// ---------------------------------------------------------------------------
// Kernel 2 (fused): attn prologue (redundant per quarter-block) + apply.
// grid = (512, 4), block = 256 -> 2048 blocks. Swizzle: XCD k owns bc
// [64k, 64k+64) == batch k, all 64 channels (contiguous 12.8 MB x region).
// ---------------------------------------------------------------------------
__device__ __forceinline__ void acc4(float4& a, float w, const float4& v) {
    a.x += w * v.x; a.y += w * v.y; a.z += w * v.z; a.w += w * v.w;
}

__global__ __launch_bounds__(256) void attn_apply_kernel(const float* __restrict__ x,
                                                         const float* __restrict__ s_ws,
                                                         const float* __restrict__ W,
                                                         const float* __restrict__ gamma,
                                                         const float* __restrict__ beta,
                                                         float* __restrict__ out) {
    __shared__ float s_lds[16 * 64];
    __shared__ float q_lds[16 * 65];    // +1 pad: conflict-free dots reads
    __shared__ float k_lds[16 * 65];
    __shared__ float A[256];            // (attn + I), row-major 16x16

    const int bc  = ((blockIdx.x & 7) << 6) | (blockIdx.x >> 3);   // bijective, 512%8==0
    const int qtr = blockIdx.y;
    const int tid = threadIdx.x;

    // ---- stage s (256 float4) -------------------------------------------
    const float4* S4 = reinterpret_cast<const float4*>(s_ws + (size_t)bc * 1024);
    reinterpret_cast<float4*>(s_lds)[tid] = S4[tid];
    __syncthreads();

    // ---- LayerNorm: row = tid>>4 (16 threads/row, 4 elems each) ---------
    {
        const int row = tid >> 4, sub = tid & 15;
        float4 v = *reinterpret_cast<const float4*>(&s_lds[row * 64 + sub * 4]);
        float sum = v.x + v.y + v.z + v.w;
        float sq  = v.x * v.x + v.y * v.y + v.z * v.z + v.w * v.w;
        #pragma unroll
        for (int off = 8; off > 0; off >>= 1) {   // stays within 16-lane row group
            sum += __shfl_xor(sum, off, 64);
            sq  += __shfl_xor(sq,  off, 64);
        }
        const float mu  = sum * (1.0f / 64.0f);
        const float var = sq * (1.0f / 64.0f) - mu * mu;
        const float rs  = rsqrtf(var + 1e-5f);
        const float4 g  = *reinterpret_cast<const float4*>(&gamma[sub * 4]);
        const float4 bt = *reinterpret_cast<const float4*>(&beta[sub * 4]);
        float4 o;
        o.x = (v.x - mu) * rs * g.x + bt.x;
        o.y = (v.y - mu) * rs * g.y + bt.y;
        o.z = (v.z - mu) * rs * g.z + bt.z;
        o.w = (v.w - mu) * rs * g.w + bt.w;
        *reinterpret_cast<float4*>(&s_lds[row * 64 + sub * 4]) = o;
    }
    __syncthreads();

    // ---- qk = s @ W: thread owns col = tid&127, rows rb..rb+7 -----------
    {
        const int col = tid & 127;
        const int rb  = (tid >> 7) * 8;
        float wcol[64];
        #pragma unroll
        for (int d = 0; d < 64; d++) wcol[d] = W[d * 128 + col];  // coalesced
        float qa[8];
        #pragma unroll
        for (int r = 0; r < 8; r++) {
            float a = 0.f;
            #pragma unroll
            for (int dd = 0; dd < 16; dd++) {
                const float4 sv = *reinterpret_cast<const float4*>(&s_lds[(rb + r) * 64 + dd * 4]);
                a += sv.x * wcol[dd * 4 + 0] + sv.y * wcol[dd * 4 + 1]
                   + sv.z * wcol[dd * 4 + 2] + sv.w * wcol[dd * 4 + 3];
            }
            qa[r] = a;
        }
        if (col < 64) {
            #pragma unroll
            for (int r = 0; r < 8; r++) q_lds[(rb + r) * 65 + col] = qa[r];
        } else {
            #pragma unroll
            for (int r = 0; r < 8; r++) k_lds[(rb + r) * 65 + (col - 64)] = qa[r];
        }
    }
    __syncthreads();

    // ---- dots + softmax: thread (i,j) owns one entry ---------------------
    {
        const int i = tid >> 4, j = tid & 15;
        float dot = 0.f;
        #pragma unroll
        for (int d = 0; d < 64; d++)
            dot += q_lds[i * 65 + d] * k_lds[j * 65 + d];
        dot *= 0.125f;
        float m = dot;
        #pragma unroll
        for (int off = 8; off > 0; off >>= 1)
            m = fmaxf(m, __shfl_xor(m, off, 64));
        const float e = __expf(dot - m);
        float es = e;
        #pragma unroll
        for (int off = 8; off > 0; off >>= 1)
            es += __shfl_xor(es, off, 64);
        A[i * 16 + j] = e / es + (i == j ? 1.0f : 0.0f);
    }
    __syncthreads();

    // ---- main: out[t] = sum_j A[t][j] * x[j], one f4 chunk per thread ----
    if (tid < 196) {                           // 4 * 196 = 784 f4 per plane
        const int b = bc >> 6, c = bc & 63;
        const size_t f4i = (size_t)qtr * 196 + tid;
        const float4* x4 = reinterpret_cast<const float4*>(x);
        float4* o4 = reinterpret_cast<float4*>(out);
        const size_t plane0 = ((size_t)b * 1024 + c) * HW4;

        float4 xv[16];
        #pragma unroll
        for (int j = 0; j < 16; j++)           // 16 independent streams: MLP
            xv[j] = x4[plane0 + (size_t)j * TSTRIDE4 + f4i];

        #pragma unroll
        for (int t = 0; t < 16; t++) {
            float4 a; a.x = 0.f; a.y = 0.f; a.z = 0.f; a.w = 0.f;
            #pragma unroll
            for (int jj = 0; jj < 4; jj++) {
                const float4 w4 = *reinterpret_cast<const float4*>(&A[t * 16 + jj * 4]);
                acc4(a, w4.x, xv[jj * 4 + 0]);
                acc4(a, w4.y, xv[jj * 4 + 1]);
                acc4(a, w4.z, xv[jj * 4 + 2]);
                acc4(a, w4.w, xv[jj * 4 + 3]);
            }
            o4[plane0 + (size_t)t * TSTRIDE4 + f4i] = a;   // plain store (A/B vs NT)
        }
    }
}

extern "C" void kernel_launch(void* const* d_in, const int* in_sizes, int n_in,
                              void* d_out, int out_size, void* d_ws, size_t ws_size,
                              hipStream_t stream) {
    (void)in_sizes; (void)n_in; (void)out_size; (void)ws_size;
    const float* x     = (const float*)d_in[0];
    const float* pos   = (const float*)d_in[1];
    const float* W     = (const float*)d_in[2];
    const float* gamma = (const float*)d_in[3];
    const float* beta  = (const float*)d_in[4];
    float* out = (float*)d_out;

    float* s_ws = (float*)d_ws;   // 512*16*64 = 524288 floats

    pool_kernel<<<8192, 256, 0, stream>>>(x, pos, s_ws);
    attn_apply_kernel<<<dim3(512, 4), 256, 0, stream>>>(x, s_ws, W, gamma, beta, out);
}

// Round 17
// 61.366 us; speedup vs baseline: 1.0167x; 1.0167x over previous
//
#include <hip/hip_runtime.h>
#include <hip/hip_bf16.h>
#include <math.h>

// Problem constants (from reference):
//   x: (b=8, t=16, c=64, h=56, w=56) f32   -> 25,690,112 elems
//   pos_embedding: (512, 16, 64) f32
//   W_qk: (64, 128) f32  (in, out) ; q = cols 0..63, k = cols 64..127
//   gamma, beta: (64,) f32
// out[b,t,c,f] = sum_j (softmax(q k^T * 0.125)[bc,t,j] + delta_tj) * x[b,j,c,f]
// where bc = b*64 + c, f = h*w = 3136.
//
// FINAL = R12 (best measured: 61.4 us): 2-kernel structure + T1 XCD bijective
// swizzle + NT stores (A/B'd vs plain in R16: NT 61.4 vs plain 62.4).
// Structure ceiling: pool->A->apply dependency forces 2 passes over x
// (~313 MB logical); cooperative grid-sync single-pass fails in harness.
//
// ws layout: s_ws = 512*16*64 floats (2 MB)

#define HW 3136            // 56*56
#define HW4 784            // HW/4
#define TSTRIDE4 50176     // 64*784, float4 stride between t-planes

typedef float vfloat4 __attribute__((ext_vector_type(4)));   // NT-store-able

// ---------------------------------------------------------------------------
// Kernel 1: pool each (b,t,c) plane 56x56 -> 8x8 (7x7 mean), add pos, write s.
// grid = 8192, block = 256. Swizzle: XCD k owns planes [1024k, 1024k+1024).
// ---------------------------------------------------------------------------
__global__ __launch_bounds__(256) void pool_kernel(const float* __restrict__ x,
                                                   const float* __restrict__ pos,
                                                   float* __restrict__ s_ws) {
    __shared__ float plane[HW];
    const int p   = ((blockIdx.x & 7) << 10) | (blockIdx.x >> 3);  // bijective, 8192%8==0
    const int tid = threadIdx.x;

    const float4* xp = reinterpret_cast<const float4*>(x + (size_t)p * HW);
    float4* pl4 = reinterpret_cast<float4*>(plane);
    #pragma unroll
    for (int k = 0; k < 3; k++) pl4[tid + k * 256] = xp[tid + k * 256];
    if (tid < 16) pl4[768 + tid] = xp[768 + tid];
    __syncthreads();

    if (tid < 64) {
        const int i = tid >> 3, j = tid & 7;          // 8x8 output grid
        const float* base = plane + (i * 7) * 56 + j * 7;
        float sum = 0.f;
        #pragma unroll
        for (int r = 0; r < 7; r++) {
            #pragma unroll
            for (int cc = 0; cc < 7; cc++) sum += base[r * 56 + cc];
        }
        const int c = p & 63, t = (p >> 6) & 15, b = p >> 10;
        const int bc = b * 64 + c;
        const int off = ((bc << 4) + t) * 64 + tid;   // s layout (bc, t, 64)
        s_ws[off] = sum * (1.0f / 49.0f) + pos[off];
    }
}

// ---------------------------------------------------------------------------
// Kernel 2 (fused): attn prologue (redundant per quarter-block) + apply.
// grid = (512, 4), block = 256 -> 2048 blocks. Swizzle: XCD k owns bc
// [64k, 64k+64) == batch k, all 64 channels (contiguous 12.8 MB x region).
// ---------------------------------------------------------------------------
__device__ __forceinline__ void acc4(vfloat4& a, float w, const float4& v) {
    a.x += w * v.x; a.y += w * v.y; a.z += w * v.z; a.w += w * v.w;
}

__global__ __launch_bounds__(256) void attn_apply_kernel(const float* __restrict__ x,
                                                         const float* __restrict__ s_ws,
                                                         const float* __restrict__ W,
                                                         const float* __restrict__ gamma,
                                                         const float* __restrict__ beta,
                                                         float* __restrict__ out) {
    __shared__ float s_lds[16 * 64];
    __shared__ float q_lds[16 * 65];    // +1 pad: conflict-free dots reads
    __shared__ float k_lds[16 * 65];
    __shared__ float A[256];            // (attn + I), row-major 16x16

    const int bc  = ((blockIdx.x & 7) << 6) | (blockIdx.x >> 3);   // bijective, 512%8==0
    const int qtr = blockIdx.y;
    const int tid = threadIdx.x;

    // ---- stage s (256 float4) -------------------------------------------
    const float4* S4 = reinterpret_cast<const float4*>(s_ws + (size_t)bc * 1024);
    reinterpret_cast<float4*>(s_lds)[tid] = S4[tid];
    __syncthreads();

    // ---- LayerNorm: row = tid>>4 (16 threads/row, 4 elems each) ---------
    {
        const int row = tid >> 4, sub = tid & 15;
        float4 v = *reinterpret_cast<const float4*>(&s_lds[row * 64 + sub * 4]);
        float sum = v.x + v.y + v.z + v.w;
        float sq  = v.x * v.x + v.y * v.y + v.z * v.z + v.w * v.w;
        #pragma unroll
        for (int off = 8; off > 0; off >>= 1) {   // stays within 16-lane row group
            sum += __shfl_xor(sum, off, 64);
            sq  += __shfl_xor(sq,  off, 64);
        }
        const float mu  = sum * (1.0f / 64.0f);
        const float var = sq * (1.0f / 64.0f) - mu * mu;
        const float rs  = rsqrtf(var + 1e-5f);
        const float4 g  = *reinterpret_cast<const float4*>(&gamma[sub * 4]);
        const float4 bt = *reinterpret_cast<const float4*>(&beta[sub * 4]);
        float4 o;
        o.x = (v.x - mu) * rs * g.x + bt.x;
        o.y = (v.y - mu) * rs * g.y + bt.y;
        o.z = (v.z - mu) * rs * g.z + bt.z;
        o.w = (v.w - mu) * rs * g.w + bt.w;
        *reinterpret_cast<float4*>(&s_lds[row * 64 + sub * 4]) = o;
    }
    __syncthreads();

    // ---- qk = s @ W: thread owns col = tid&127, rows rb..rb+7 -----------
    {
        const int col = tid & 127;
        const int rb  = (tid >> 7) * 8;
        float wcol[64];
        #pragma unroll
        for (int d = 0; d < 64; d++) wcol[d] = W[d * 128 + col];  // coalesced
        float qa[8];
        #pragma unroll
        for (int r = 0; r < 8; r++) {
            float a = 0.f;
            #pragma unroll
            for (int dd = 0; dd < 16; dd++) {
                const float4 sv = *reinterpret_cast<const float4*>(&s_lds[(rb + r) * 64 + dd * 4]);
                a += sv.x * wcol[dd * 4 + 0] + sv.y * wcol[dd * 4 + 1]
                   + sv.z * wcol[dd * 4 + 2] + sv.w * wcol[dd * 4 + 3];
            }
            qa[r] = a;
        }
        if (col < 64) {
            #pragma unroll
            for (int r = 0; r < 8; r++) q_lds[(rb + r) * 65 + col] = qa[r];
        } else {
            #pragma unroll
            for (int r = 0; r < 8; r++) k_lds[(rb + r) * 65 + (col - 64)] = qa[r];
        }
    }
    __syncthreads();

    // ---- dots + softmax: thread (i,j) owns one entry ---------------------
    {
        const int i = tid >> 4, j = tid & 15;
        float dot = 0.f;
        #pragma unroll
        for (int d = 0; d < 64; d++)
            dot += q_lds[i * 65 + d] * k_lds[j * 65 + d];
        dot *= 0.125f;
        float m = dot;
        #pragma unroll
        for (int off = 8; off > 0; off >>= 1)
            m = fmaxf(m, __shfl_xor(m, off, 64));
        const float e = __expf(dot - m);
        float es = e;
        #pragma unroll
        for (int off = 8; off > 0; off >>= 1)
            es += __shfl_xor(es, off, 64);
        A[i * 16 + j] = e / es + (i == j ? 1.0f : 0.0f);
    }
    __syncthreads();

    // ---- main: out[t] = sum_j A[t][j] * x[j], one f4 chunk per thread ----
    if (tid < 196) {                           // 4 * 196 = 784 f4 per plane
        const int b = bc >> 6, c = bc & 63;
        const size_t f4i = (size_t)qtr * 196 + tid;
        const float4* x4 = reinterpret_cast<const float4*>(x);
        vfloat4* o4 = reinterpret_cast<vfloat4*>(out);
        const size_t plane0 = ((size_t)b * 1024 + c) * HW4;

        float4 xv[16];
        #pragma unroll
        for (int j = 0; j < 16; j++)           // 16 independent streams: MLP
            xv[j] = x4[plane0 + (size_t)j * TSTRIDE4 + f4i];

        #pragma unroll
        for (int t = 0; t < 16; t++) {
            vfloat4 a = (vfloat4)(0.f);
            #pragma unroll
            for (int jj = 0; jj < 4; jj++) {
                const float4 w4 = *reinterpret_cast<const float4*>(&A[t * 16 + jj * 4]);
                acc4(a, w4.x, xv[jj * 4 + 0]);
                acc4(a, w4.y, xv[jj * 4 + 1]);
                acc4(a, w4.z, xv[jj * 4 + 2]);
                acc4(a, w4.w, xv[jj * 4 + 3]);
            }
            __builtin_nontemporal_store(a, &o4[plane0 + (size_t)t * TSTRIDE4 + f4i]);
        }
    }
}

extern "C" void kernel_launch(void* const* d_in, const int* in_sizes, int n_in,
                              void* d_out, int out_size, void* d_ws, size_t ws_size,
                              hipStream_t stream) {
    (void)in_sizes; (void)n_in; (void)out_size; (void)ws_size;
    const float* x     = (const float*)d_in[0];
    const float* pos   = (const float*)d_in[1];
    const float* W     = (const float*)d_in[2];
    const float* gamma = (const float*)d_in[3];
    const float* beta  = (const float*)d_in[4];
    float* out = (float*)d_out;

    float* s_ws = (float*)d_ws;   // 512*16*64 = 524288 floats

    pool_kernel<<<8192, 256, 0, stream>>>(x, pos, s_ws);
    attn_apply_kernel<<<dim3(512, 4), 256, 0, stream>>>(x, s_ws, W, gamma, beta, out);
}